// Round 8
// baseline (265.219 us; speedup 1.0000x reference)
//
#include <hip/hip_runtime.h>

// LSTM text classifier: emb-gather -> LSTM(512 steps) -> FC(32->2)
//   K1 build_ptab: ptab[v] = (emb[v] @ w_ih^T + b_ih + b_hh) * gate_scale  (packed float2)
//   K2 lstm_scan: 1 wave per batch element; amdgpu_waves_per_eu(1,1) (R6 fix,
//       verified VGPR 132) so weights stay register-resident.
//   R8 (fixes R7 compile error): v_pk_fma_f32 is VOP3P -> ALL sources must be
//       64-bit pairs. Pack over K instead of over gates: swizzle pair
//       {h_{c^2m}, h_{c^(2m+1)}} is a natural register pair (ds_swizzle writes
//       directly into both halves, no dup-mov). 32 pk_fma + 31 ds_swizzle per
//       step; h fanout rides the LDS pipe, FMA issue halves vs R6.

#define LOG2E 1.44269504088896340736f

typedef float f32x2 __attribute__((ext_vector_type(2)));
typedef unsigned uv2 __attribute__((ext_vector_type(2)));
typedef float f32x32 __attribute__((ext_vector_type(32)));

__device__ __forceinline__ float fast_rcp(float x) { return __builtin_amdgcn_rcpf(x); }
__device__ __forceinline__ float fast_exp2(float x) { return __builtin_amdgcn_exp2f(x); }

// permlane32_swap(x,x): r.x = lo-half value in ALL lanes, r.y = hi-half value
// in ALL lanes. (r.y verified on HW since R2; r.x from the same swap semantics:
// vdst keeps its lo lanes (=x.lo) and receives src.lo into its hi lanes.)
__device__ __forceinline__ f32x2 bcast_both(float x) {
    uv2 r = __builtin_amdgcn_permlane32_swap(__float_as_uint(x), __float_as_uint(x),
                                             false, false);
    f32x2 o;
    o.x = __uint_as_float(r.x);  // lo value, all lanes
    o.y = __uint_as_float(r.y);  // hi value, all lanes
    return o;
}

// ds_swizzle XOR-k within each 32-lane half (BitMode: offset=(xor<<10)|and(0x1F))
#define SWZ(V, K)                                                              \
    __uint_as_float((unsigned)__builtin_amdgcn_ds_swizzle(                     \
        (int)__float_as_uint(V), (((K) << 10) | 0x1F)))

// acc = w * hk + acc, all three 64-bit pairs (legal VOP3P operands)
#define PKFMA(ACC, W, HK)                                                      \
    {                                                                          \
        f32x2 _d;                                                              \
        asm("v_pk_fma_f32 %0, %1, %2, %3"                                      \
            : "=v"(_d)                                                         \
            : "v"(W), "v"(HK), "v"(ACC));                                      \
        ACC = _d;                                                              \
    }

// ---------------- K1: projected + prescaled embedding table ----------------
__global__ __launch_bounds__(64, 1) void build_ptab(
    const float4* __restrict__ emb4, const float4* __restrict__ wih4,
    const float* __restrict__ bih, const float* __restrict__ bhh,
    float2* __restrict__ ptab, int nrows) {
    const int lane = threadIdx.x;

    float w0[32], w1[32];
#pragma unroll
    for (int q = 0; q < 8; ++q) {
        float4 a = wih4[lane * 8 + q];
        float4 b = wih4[(lane + 64) * 8 + q];
        w0[4 * q + 0] = a.x; w0[4 * q + 1] = a.y; w0[4 * q + 2] = a.z; w0[4 * q + 3] = a.w;
        w1[4 * q + 0] = b.x; w1[4 * q + 1] = b.y; w1[4 * q + 2] = b.z; w1[4 * q + 3] = b.w;
    }
    const float bias0 = bih[lane] + bhh[lane];
    const float bias1 = bih[lane + 64] + bhh[lane + 64];
    const float s0 = -LOG2E;                                   // rows l: i,f -> sigmoid
    const float s1 = (lane < 32) ? (2.0f * LOG2E) : (-LOG2E);  // rows l+64: g tanh / o sigmoid

    for (int v = blockIdx.x; v < nrows; v += gridDim.x) {
        float a0 = bias0, a1 = bias1;
#pragma unroll
        for (int q = 0; q < 8; ++q) {
            float4 e = emb4[v * 8 + q];  // wave-uniform -> cache broadcast
            a0 = fmaf(e.x, w0[4 * q + 0], a0);
            a0 = fmaf(e.y, w0[4 * q + 1], a0);
            a0 = fmaf(e.z, w0[4 * q + 2], a0);
            a0 = fmaf(e.w, w0[4 * q + 3], a0);
            a1 = fmaf(e.x, w1[4 * q + 0], a1);
            a1 = fmaf(e.y, w1[4 * q + 1], a1);
            a1 = fmaf(e.z, w1[4 * q + 2], a1);
            a1 = fmaf(e.w, w1[4 * q + 3], a1);
        }
        ptab[v * 64 + lane] = make_float2(a0 * s0, a1 * s1);  // coalesced 512B/row
    }
}

// ---- 16 k-pairs (m = 0..15 covers k = 2m, 2m+1) ----
#define REP16(M) M(0) M(1) M(2) M(3) M(4) M(5) M(6) M(7) M(8) M(9) M(10) M(11) \
    M(12) M(13) M(14) M(15)

// packed recurrent weights, k-pair m:
//   w0_m = { W[l][c0]*s0,  W[l][c0^1]*s0 }   (row l)
//   w1_m = { W[l+64][c0]*s1, W[l+64][c0^1]*s1 } (row l+64),  c0 = (lane&31)^(2m)
#define WDECL(M) f32x2 w0_##M, w1_##M;
#define WLOAD(M)                                                               \
    {                                                                          \
        int _c0 = (lane & 31) ^ (2 * (M));                                     \
        int _c1 = _c0 ^ 1;                                                     \
        w0_##M.x = whh[(size_t)lane * 32 + _c0] * s0;                          \
        w0_##M.y = whh[(size_t)lane * 32 + _c1] * s0;                          \
        w1_##M.x = whh[((size_t)lane + 64) * 32 + _c0] * s1;                   \
        w1_##M.y = whh[((size_t)lane + 64) * 32 + _c1] * s1;                   \
    }

// one k-pair: 2 swizzles into a natural register pair, 2 packed FMAs
#define DOTP(M, ACC0, ACC1)                                                    \
    {                                                                          \
        f32x2 _hk;                                                             \
        _hk.x = SWZ(h, 2 * (M));                                               \
        _hk.y = SWZ(h, 2 * (M) + 1);                                           \
        PKFMA(ACC0, w0_##M, _hk);                                              \
        PKFMA(ACC1, w1_##M, _hk);                                              \
    }

// one LSTM step; P = packed {g0,g1} prescaled pre-activations.
// Uses kernel-scope h, cs, w0_0..w0_15, w1_0..w1_15.
// h,cs valid in ALL 64 lanes (periodic-32). cs = c * 2*log2e.
#define STEP(P)                                                                \
    do {                                                                       \
        f32x2 _acc00, _acc01 = (f32x2)(0.0f);                                  \
        f32x2 _acc10, _acc11 = (f32x2)(0.0f);                                  \
        _acc00.x = (P).x; _acc00.y = 0.0f;                                     \
        _acc10.x = (P).y; _acc10.y = 0.0f;                                     \
        { /* pair 0: k=0 is identity (h itself), k=1 swizzled */               \
            f32x2 _hk;                                                         \
            _hk.x = h;                                                         \
            _hk.y = SWZ(h, 1);                                                 \
            PKFMA(_acc00, w0_0, _hk);                                          \
            PKFMA(_acc10, w1_0, _hk);                                          \
        }                                                                      \
        DOTP(1, _acc01, _acc11) DOTP(2, _acc00, _acc10)                        \
        DOTP(3, _acc01, _acc11) DOTP(4, _acc00, _acc10)                        \
        DOTP(5, _acc01, _acc11) DOTP(6, _acc00, _acc10)                        \
        DOTP(7, _acc01, _acc11) DOTP(8, _acc00, _acc10)                        \
        DOTP(9, _acc01, _acc11) DOTP(10, _acc00, _acc10)                       \
        DOTP(11, _acc01, _acc11) DOTP(12, _acc00, _acc10)                      \
        DOTP(13, _acc01, _acc11) DOTP(14, _acc00, _acc10)                      \
        DOTP(15, _acc01, _acc11)                                               \
        f32x2 _s0 = _acc00 + _acc01;                                           \
        f32x2 _s1 = _acc10 + _acc11;                                           \
        float _A0 = _s0.x + _s0.y; /* lo: y_i*s0, hi: y_f*s0 */                \
        float _A1 = _s1.x + _s1.y; /* lo: y_g*s1, hi: y_o*s1 */                \
        float _sg = fast_rcp(1.0f + fast_exp2(_A0)); /* lo:i  hi:f */          \
        float _r1 = fast_rcp(1.0f + fast_exp2(_A1)); /* lo:gf hi:o */          \
        f32x2 _bs = bcast_both(_sg); /* .x=i .y=f (all lanes) */               \
        f32x2 _br = bcast_both(_r1); /* .x=gf .y=o (all lanes) */              \
        float _ggs = fmaf(-4.0f * LOG2E, _br.x, 2.0f * LOG2E); /* tanh(g)*2log2e */ \
        cs = fmaf(_bs.y, cs, _bs.x * _ggs);                                    \
        h = _br.y * fmaf(-2.0f, fast_rcp(1.0f + fast_exp2(cs)), 1.0f);         \
    } while (0)

// ---------------- K2: LSTM scan, one wave per batch element ----------------
template <bool PTAB>
__global__ __launch_bounds__(64)
__attribute__((amdgpu_waves_per_eu(1, 1)))  // pressure target = 1 wave/EU (R6, verified)
void lstm_scan(
    const int* __restrict__ x,
    const float2* __restrict__ ptab,
    const float* __restrict__ emb,
    const float* __restrict__ wih,
    const float* __restrict__ bih,
    const float* __restrict__ bhh,
    const float* __restrict__ whh,
    const float* __restrict__ fcw,
    const float* __restrict__ fcb,
    float* __restrict__ out,
    int S) {
    extern __shared__ int xrow[];
    const int b = blockIdx.x;
    const int lane = threadIdx.x;

    // token ids in LDS, padded so the prefetch ring never reads OOB
    for (int i = lane; i < S + 16; i += 64) xrow[i] = (i < S) ? x[(size_t)b * S + i] : 0;
    __syncthreads();

    const float s0 = -LOG2E;
    const float s1 = (lane < 32) ? (2.0f * LOG2E) : (-LOG2E);

    REP16(WDECL)
    REP16(WLOAD)

    float h = 0.0f, cs = 0.0f;  // valid in all 64 lanes (periodic-32); cs = c*2log2e

    if constexpr (PTAB) {
        // 32-bit offset addressing: ptab is 25.6MB, idx<<9 fits unsigned
        const char* pb = (const char*)ptab + (unsigned)(lane << 3);
        // p ring = pre-activations for steps t..t+3; i ring = tokens t+4..t+7
        int i0 = xrow[4], i1 = xrow[5], i2 = xrow[6], i3 = xrow[7];
        f32x2 p0 = *(const f32x2*)(pb + ((unsigned)xrow[0] << 9));
        f32x2 p1 = *(const f32x2*)(pb + ((unsigned)xrow[1] << 9));
        f32x2 p2 = *(const f32x2*)(pb + ((unsigned)xrow[2] << 9));
        f32x2 p3 = *(const f32x2*)(pb + ((unsigned)xrow[3] << 9));
        int t = 0;
        for (; t + 8 <= S; t += 4) {
            STEP(p0); p0 = *(const f32x2*)(pb + ((unsigned)i0 << 9)); i0 = xrow[t + 8];
            STEP(p1); p1 = *(const f32x2*)(pb + ((unsigned)i1 << 9)); i1 = xrow[t + 9];
            STEP(p2); p2 = *(const f32x2*)(pb + ((unsigned)i2 << 9)); i2 = xrow[t + 10];
            STEP(p3); p3 = *(const f32x2*)(pb + ((unsigned)i3 << 9)); i3 = xrow[t + 11];
        }
        if (t + 0 < S) STEP(p0);
        if (t + 1 < S) STEP(p1);
        if (t + 2 < S) STEP(p2);
        if (t + 3 < S) STEP(p3);
        if (t + 4 < S) { f32x2 q = *(const f32x2*)(pb + ((unsigned)i0 << 9)); STEP(q); }
        if (t + 5 < S) { f32x2 q = *(const f32x2*)(pb + ((unsigned)i1 << 9)); STEP(q); }
        if (t + 6 < S) { f32x2 q = *(const f32x2*)(pb + ((unsigned)i2 << 9)); STEP(q); }
    } else {
        // fallback: on-the-fly input projection (workspace too small); cold path
        f32x32 wi0, wi1;
        {
            const float4* wih4 = (const float4*)wih;
#pragma unroll
            for (int q = 0; q < 8; ++q) {
                float4 a = wih4[lane * 8 + q];
                float4 bb = wih4[(lane + 64) * 8 + q];
                wi0[4 * q + 0] = a.x * s0; wi0[4 * q + 1] = a.y * s0;
                wi0[4 * q + 2] = a.z * s0; wi0[4 * q + 3] = a.w * s0;
                wi1[4 * q + 0] = bb.x * s1; wi1[4 * q + 1] = bb.y * s1;
                wi1[4 * q + 2] = bb.z * s1; wi1[4 * q + 3] = bb.w * s1;
            }
        }
        const float bias0 = (bih[lane] + bhh[lane]) * s0;
        const float bias1 = (bih[lane + 64] + bhh[lane + 64]) * s1;
        const float4* emb4 = (const float4*)emb;
        for (int t = 0; t < S; ++t) {
            int idx = xrow[t];
            float a0 = bias0, a1 = bias1;
#pragma unroll
            for (int q = 0; q < 8; ++q) {
                float4 e = emb4[(size_t)idx * 8 + q];
                a0 = fmaf(e.x, wi0[4 * q + 0], a0);
                a0 = fmaf(e.y, wi0[4 * q + 1], a0);
                a0 = fmaf(e.z, wi0[4 * q + 2], a0);
                a0 = fmaf(e.w, wi0[4 * q + 3], a0);
                a1 = fmaf(e.x, wi1[4 * q + 0], a1);
                a1 = fmaf(e.y, wi1[4 * q + 1], a1);
                a1 = fmaf(e.z, wi1[4 * q + 2], a1);
                a1 = fmaf(e.w, wi1[4 * q + 3], a1);
            }
            f32x2 _p; _p.x = a0; _p.y = a1;
            STEP(_p);
        }
    }

    // FC: out[b][n] = sum_k h_k * fc_w[n][k] + fc_b[n]; h periodic-32 ->
    // mask to lanes 0..31 to avoid double counting
    float wv0 = fcw[lane & 31];
    float wv1 = fcw[32 + (lane & 31)];
    float p0v = (lane < 32) ? h * wv0 : 0.0f;
    float p1v = (lane < 32) ? h * wv1 : 0.0f;
#pragma unroll
    for (int m = 32; m >= 1; m >>= 1) {
        p0v += __shfl_xor(p0v, m, 64);
        p1v += __shfl_xor(p1v, m, 64);
    }
    if (lane == 0) {
        out[b * 2 + 0] = p0v + fcb[0];
        out[b * 2 + 1] = p1v + fcb[1];
    }
}

extern "C" void kernel_launch(void* const* d_in, const int* in_sizes, int n_in,
                              void* d_out, int out_size, void* d_ws, size_t ws_size,
                              hipStream_t stream) {
    const int* x = (const int*)d_in[0];
    const float* emb = (const float*)d_in[1];
    const float* wih = (const float*)d_in[2];
    const float* whh = (const float*)d_in[3];
    const float* bih = (const float*)d_in[4];
    const float* bhh = (const float*)d_in[5];
    const float* fcw = (const float*)d_in[6];
    const float* fcb = (const float*)d_in[7];
    float* out = (float*)d_out;

    const int B = out_size / 2;          // 1024
    const int S = in_sizes[0] / B;       // 512
    const int nrows = in_sizes[1] / 32;  // 50001 (EMB=32)

    const size_t need = (size_t)nrows * 64 * sizeof(float2);  // 25.6 MB
    const size_t smem = (size_t)(S + 16) * sizeof(int);

    if (ws_size >= need) {
        float2* ptab = (float2*)d_ws;
        int nb = nrows < 4096 ? nrows : 4096;
        build_ptab<<<nb, 64, 0, stream>>>((const float4*)emb, (const float4*)wih,
                                          bih, bhh, ptab, nrows);
        lstm_scan<true><<<B, 64, smem, stream>>>(x, ptab, emb, wih, bih, bhh, whh,
                                                 fcw, fcb, out, S);
    } else {
        lstm_scan<false><<<B, 64, smem, stream>>>(x, nullptr, emb, wih, bih, bhh, whh,
                                                  fcw, fcb, out, S);
    }
}

// Round 9
// 177.070 us; speedup vs baseline: 1.4978x; 1.4978x over previous
//
#include <hip/hip_runtime.h>

// LSTM text classifier: emb-gather -> LSTM(512 steps) -> FC(32->2)
//   K1 build_ptab: ptab[v] = (emb[v] @ w_ih^T + b_ih + b_hh) * gate_scale  (packed float2)
//   K2 lstm_scan: 1 wave per batch element; amdgpu_waves_per_eu(1,1) (R6 fix,
//       verified VGPR 132 / weights resident).
//   R9: dot engine = k-packed v_pk_fma_f32 with SGPR-PAIR h operand.
//       R8 lesson: at 1 wave/SIMD the LDS pipe (ds_swizzle) has unhidable
//       latency (23% VALUBusy, 1205 cyc/step). Cross-lane stays on
//       readlane->SGPR (R6, best measured). Two readlanes {h_2m,h_2m+1} form
//       a natural adjacent SGPR pair = legal VOP3P scalar source; one pk_fma
//       covers 2 k's -> dot issue halves (96 -> 64 instr).
//       Tail = R8's all-lane form (bcast_both + cs-state), HW-verified absmax 0.

#define LOG2E 1.44269504088896340736f

typedef float f32x2 __attribute__((ext_vector_type(2)));
typedef unsigned uv2 __attribute__((ext_vector_type(2)));
typedef float f32x32 __attribute__((ext_vector_type(32)));

__device__ __forceinline__ float fast_rcp(float x) { return __builtin_amdgcn_rcpf(x); }
__device__ __forceinline__ float fast_exp2(float x) { return __builtin_amdgcn_exp2f(x); }

// permlane32_swap(x,x): r.x = lo-half value in ALL lanes, r.y = hi-half value
// in ALL lanes. HW-verified (R8 ran this exact form, absmax 0.0).
__device__ __forceinline__ f32x2 bcast_both(float x) {
    uv2 r = __builtin_amdgcn_permlane32_swap(__float_as_uint(x), __float_as_uint(x),
                                             false, false);
    f32x2 o;
    o.x = __uint_as_float(r.x);  // lo value, all lanes
    o.y = __uint_as_float(r.y);  // hi value, all lanes
    return o;
}

// ---------------- K1: projected + prescaled embedding table ----------------
__global__ __launch_bounds__(64, 1) void build_ptab(
    const float4* __restrict__ emb4, const float4* __restrict__ wih4,
    const float* __restrict__ bih, const float* __restrict__ bhh,
    float2* __restrict__ ptab, int nrows) {
    const int lane = threadIdx.x;

    float w0[32], w1[32];
#pragma unroll
    for (int q = 0; q < 8; ++q) {
        float4 a = wih4[lane * 8 + q];
        float4 b = wih4[(lane + 64) * 8 + q];
        w0[4 * q + 0] = a.x; w0[4 * q + 1] = a.y; w0[4 * q + 2] = a.z; w0[4 * q + 3] = a.w;
        w1[4 * q + 0] = b.x; w1[4 * q + 1] = b.y; w1[4 * q + 2] = b.z; w1[4 * q + 3] = b.w;
    }
    const float bias0 = bih[lane] + bhh[lane];
    const float bias1 = bih[lane + 64] + bhh[lane + 64];
    const float s0 = -LOG2E;                                   // rows l: i,f -> sigmoid
    const float s1 = (lane < 32) ? (2.0f * LOG2E) : (-LOG2E);  // rows l+64: g tanh / o sigmoid

    for (int v = blockIdx.x; v < nrows; v += gridDim.x) {
        float a0 = bias0, a1 = bias1;
#pragma unroll
        for (int q = 0; q < 8; ++q) {
            float4 e = emb4[v * 8 + q];  // wave-uniform -> cache broadcast
            a0 = fmaf(e.x, w0[4 * q + 0], a0);
            a0 = fmaf(e.y, w0[4 * q + 1], a0);
            a0 = fmaf(e.z, w0[4 * q + 2], a0);
            a0 = fmaf(e.w, w0[4 * q + 3], a0);
            a1 = fmaf(e.x, w1[4 * q + 0], a1);
            a1 = fmaf(e.y, w1[4 * q + 1], a1);
            a1 = fmaf(e.z, w1[4 * q + 2], a1);
            a1 = fmaf(e.w, w1[4 * q + 3], a1);
        }
        ptab[v * 64 + lane] = make_float2(a0 * s0, a1 * s1);  // coalesced 512B/row
    }
}

// one k-pair: 2 readlanes (adjacent SGPRs -> 64-bit scalar pair), 2 packed FMAs
// covering k = 2M, 2M+1 for both gate rows. Uses kernel-scope h, w0[], w1[].
#define KPAIR(M, ACC0, ACC1)                                                   \
    {                                                                          \
        unsigned _lo = __builtin_amdgcn_readlane(__float_as_uint(h), 2 * (M)); \
        unsigned _hi = __builtin_amdgcn_readlane(__float_as_uint(h), 2 * (M) + 1); \
        unsigned long long _hp = ((unsigned long long)_hi << 32) | _lo;        \
        asm("v_pk_fma_f32 %0, %1, %2, %0"                                      \
            : "+v"(ACC0)                                                       \
            : "v"(w0[M]), "s"(_hp));                                           \
        asm("v_pk_fma_f32 %0, %1, %2, %0"                                      \
            : "+v"(ACC1)                                                       \
            : "v"(w1[M]), "s"(_hp));                                           \
    }

// one LSTM step; P = packed {g0,g1} prescaled pre-activations.
// h, cs valid in ALL 64 lanes (periodic-32); cs = c * 2*log2e. Tail = R8 (verified).
#define STEP(P)                                                                \
    do {                                                                       \
        f32x2 _accA0, _accA1 = (f32x2)(0.0f);                                  \
        f32x2 _accB0, _accB1 = (f32x2)(0.0f);                                  \
        _accA0.x = (P).x; _accA0.y = 0.0f;                                     \
        _accB0.x = (P).y; _accB0.y = 0.0f;                                     \
        KPAIR(0, _accA0, _accB0) KPAIR(1, _accA1, _accB1)                      \
        KPAIR(2, _accA0, _accB0) KPAIR(3, _accA1, _accB1)                      \
        KPAIR(4, _accA0, _accB0) KPAIR(5, _accA1, _accB1)                      \
        KPAIR(6, _accA0, _accB0) KPAIR(7, _accA1, _accB1)                      \
        KPAIR(8, _accA0, _accB0) KPAIR(9, _accA1, _accB1)                      \
        KPAIR(10, _accA0, _accB0) KPAIR(11, _accA1, _accB1)                    \
        KPAIR(12, _accA0, _accB0) KPAIR(13, _accA1, _accB1)                    \
        KPAIR(14, _accA0, _accB0) KPAIR(15, _accA1, _accB1)                    \
        f32x2 _sA = _accA0 + _accA1;                                           \
        f32x2 _sB = _accB0 + _accB1;                                           \
        float _A0 = _sA.x + _sA.y; /* lo: y_i*s0, hi: y_f*s0 */                \
        float _A1 = _sB.x + _sB.y; /* lo: y_g*s1, hi: y_o*s1 */                \
        float _sg = fast_rcp(1.0f + fast_exp2(_A0)); /* lo:i  hi:f */          \
        float _r1 = fast_rcp(1.0f + fast_exp2(_A1)); /* lo:gf hi:o */          \
        f32x2 _bs = bcast_both(_sg); /* .x=i .y=f (all lanes) */               \
        f32x2 _br = bcast_both(_r1); /* .x=gf .y=o (all lanes) */              \
        float _ggs = fmaf(-4.0f * LOG2E, _br.x, 2.0f * LOG2E); /* tanh(g)*2log2e */ \
        cs = fmaf(_bs.y, cs, _bs.x * _ggs);                                    \
        h = _br.y * fmaf(-2.0f, fast_rcp(1.0f + fast_exp2(cs)), 1.0f);         \
    } while (0)

// ---------------- K2: LSTM scan, one wave per batch element ----------------
template <bool PTAB>
__global__ __launch_bounds__(64)
__attribute__((amdgpu_waves_per_eu(1, 1)))  // pressure target = 1 wave/EU (R6, verified)
void lstm_scan(
    const int* __restrict__ x,
    const float2* __restrict__ ptab,
    const float* __restrict__ emb,
    const float* __restrict__ wih,
    const float* __restrict__ bih,
    const float* __restrict__ bhh,
    const float* __restrict__ whh,
    const float* __restrict__ fcw,
    const float* __restrict__ fcb,
    float* __restrict__ out,
    int S) {
    extern __shared__ int xrow[];
    const int b = blockIdx.x;
    const int lane = threadIdx.x;

    // token ids in LDS, padded so the prefetch ring never reads OOB
    for (int i = lane; i < S + 16; i += 64) xrow[i] = (i < S) ? x[(size_t)b * S + i] : 0;
    __syncthreads();

    const float s0 = -LOG2E;
    const float s1 = (lane < 32) ? (2.0f * LOG2E) : (-LOG2E);

    // recurrent weights, k-packed: w0[m] = {W[l][2m],W[l][2m+1]}*s0 (row l),
    // w1[m] likewise for row l+64 with s1. Constant indices only (SROA-safe).
    f32x2 w0[16], w1[16];
    {
        const float4* whh4 = (const float4*)whh;
#pragma unroll
        for (int q = 0; q < 8; ++q) {
            float4 a = whh4[lane * 8 + q];
            float4 bb = whh4[(lane + 64) * 8 + q];
            w0[2 * q + 0].x = a.x * s0;  w0[2 * q + 0].y = a.y * s0;
            w0[2 * q + 1].x = a.z * s0;  w0[2 * q + 1].y = a.w * s0;
            w1[2 * q + 0].x = bb.x * s1; w1[2 * q + 0].y = bb.y * s1;
            w1[2 * q + 1].x = bb.z * s1; w1[2 * q + 1].y = bb.w * s1;
        }
    }

    float h = 0.0f, cs = 0.0f;  // valid in all 64 lanes (periodic-32); cs = c*2log2e

    if constexpr (PTAB) {
        // 32-bit offset addressing: ptab is 25.6MB, idx<<9 fits unsigned
        const char* pb = (const char*)ptab + (unsigned)(lane << 3);
        // p ring = pre-activations for steps t..t+3; i ring = tokens t+4..t+7
        int i0 = xrow[4], i1 = xrow[5], i2 = xrow[6], i3 = xrow[7];
        f32x2 p0 = *(const f32x2*)(pb + ((unsigned)xrow[0] << 9));
        f32x2 p1 = *(const f32x2*)(pb + ((unsigned)xrow[1] << 9));
        f32x2 p2 = *(const f32x2*)(pb + ((unsigned)xrow[2] << 9));
        f32x2 p3 = *(const f32x2*)(pb + ((unsigned)xrow[3] << 9));
        int t = 0;
        for (; t + 8 <= S; t += 4) {
            STEP(p0); p0 = *(const f32x2*)(pb + ((unsigned)i0 << 9)); i0 = xrow[t + 8];
            STEP(p1); p1 = *(const f32x2*)(pb + ((unsigned)i1 << 9)); i1 = xrow[t + 9];
            STEP(p2); p2 = *(const f32x2*)(pb + ((unsigned)i2 << 9)); i2 = xrow[t + 10];
            STEP(p3); p3 = *(const f32x2*)(pb + ((unsigned)i3 << 9)); i3 = xrow[t + 11];
        }
        if (t + 0 < S) STEP(p0);
        if (t + 1 < S) STEP(p1);
        if (t + 2 < S) STEP(p2);
        if (t + 3 < S) STEP(p3);
        if (t + 4 < S) { f32x2 q = *(const f32x2*)(pb + ((unsigned)i0 << 9)); STEP(q); }
        if (t + 5 < S) { f32x2 q = *(const f32x2*)(pb + ((unsigned)i1 << 9)); STEP(q); }
        if (t + 6 < S) { f32x2 q = *(const f32x2*)(pb + ((unsigned)i2 << 9)); STEP(q); }
    } else {
        // fallback: on-the-fly input projection (workspace too small); cold path
        f32x32 wi0, wi1;
        {
            const float4* wih4 = (const float4*)wih;
#pragma unroll
            for (int q = 0; q < 8; ++q) {
                float4 a = wih4[lane * 8 + q];
                float4 bb = wih4[(lane + 64) * 8 + q];
                wi0[4 * q + 0] = a.x * s0; wi0[4 * q + 1] = a.y * s0;
                wi0[4 * q + 2] = a.z * s0; wi0[4 * q + 3] = a.w * s0;
                wi1[4 * q + 0] = bb.x * s1; wi1[4 * q + 1] = bb.y * s1;
                wi1[4 * q + 2] = bb.z * s1; wi1[4 * q + 3] = bb.w * s1;
            }
        }
        const float bias0 = (bih[lane] + bhh[lane]) * s0;
        const float bias1 = (bih[lane + 64] + bhh[lane + 64]) * s1;
        const float4* emb4 = (const float4*)emb;
        for (int t = 0; t < S; ++t) {
            int idx = xrow[t];
            float a0 = bias0, a1 = bias1;
#pragma unroll
            for (int q = 0; q < 8; ++q) {
                float4 e = emb4[(size_t)idx * 8 + q];
                a0 = fmaf(e.x, wi0[4 * q + 0], a0);
                a0 = fmaf(e.y, wi0[4 * q + 1], a0);
                a0 = fmaf(e.z, wi0[4 * q + 2], a0);
                a0 = fmaf(e.w, wi0[4 * q + 3], a0);
                a1 = fmaf(e.x, wi1[4 * q + 0], a1);
                a1 = fmaf(e.y, wi1[4 * q + 1], a1);
                a1 = fmaf(e.z, wi1[4 * q + 2], a1);
                a1 = fmaf(e.w, wi1[4 * q + 3], a1);
            }
            f32x2 _p; _p.x = a0; _p.y = a1;
            STEP(_p);
        }
    }

    // FC: out[b][n] = sum_k h_k * fc_w[n][k] + fc_b[n]; h periodic-32 ->
    // mask to lanes 0..31 to avoid double counting
    float wv0 = fcw[lane & 31];
    float wv1 = fcw[32 + (lane & 31)];
    float p0v = (lane < 32) ? h * wv0 : 0.0f;
    float p1v = (lane < 32) ? h * wv1 : 0.0f;
#pragma unroll
    for (int m = 32; m >= 1; m >>= 1) {
        p0v += __shfl_xor(p0v, m, 64);
        p1v += __shfl_xor(p1v, m, 64);
    }
    if (lane == 0) {
        out[b * 2 + 0] = p0v + fcb[0];
        out[b * 2 + 1] = p1v + fcb[1];
    }
}

extern "C" void kernel_launch(void* const* d_in, const int* in_sizes, int n_in,
                              void* d_out, int out_size, void* d_ws, size_t ws_size,
                              hipStream_t stream) {
    const int* x = (const int*)d_in[0];
    const float* emb = (const float*)d_in[1];
    const float* wih = (const float*)d_in[2];
    const float* whh = (const float*)d_in[3];
    const float* bih = (const float*)d_in[4];
    const float* bhh = (const float*)d_in[5];
    const float* fcw = (const float*)d_in[6];
    const float* fcb = (const float*)d_in[7];
    float* out = (float*)d_out;

    const int B = out_size / 2;          // 1024
    const int S = in_sizes[0] / B;       // 512
    const int nrows = in_sizes[1] / 32;  // 50001 (EMB=32)

    const size_t need = (size_t)nrows * 64 * sizeof(float2);  // 25.6 MB
    const size_t smem = (size_t)(S + 16) * sizeof(int);

    if (ws_size >= need) {
        float2* ptab = (float2*)d_ws;
        int nb = nrows < 8192 ? nrows : 8192;
        build_ptab<<<nb, 64, 0, stream>>>((const float4*)emb, (const float4*)wih,
                                          bih, bhh, ptab, nrows);
        lstm_scan<true><<<B, 64, smem, stream>>>(x, ptab, emb, wih, bih, bhh, whh,
                                                 fcw, fcb, out, S);
    } else {
        lstm_scan<false><<<B, 64, smem, stream>>>(x, nullptr, emb, wih, bih, bhh, whh,
                                                  fcw, fcb, out, S);
    }
}

// Round 10
// 138.992 us; speedup vs baseline: 1.9082x; 1.2740x over previous
//
#include <hip/hip_runtime.h>

// LSTM text classifier: emb-gather -> LSTM(512 steps) -> FC(32->2)
//   K1 build_ptab: ptab[v] = (emb[v] @ w_ih^T + b_ih + b_hh) * gate_scale  (packed float2)
//   K2 lstm_scan: 1 wave per batch element; amdgpu_waves_per_eu(1,1) (R6,
//       verified: weights register-resident, VGPR 132).
//   R10: systolic dot, dual-direction. R9 proved pk_fma has no issue benefit
//       (half-rate pipe; busy 423 = R6's 427). R6's cost center is 32
//       v_readlane (~130 cyc + VALU->SGPR hazards). Replace with 31 full-rate
//       DPP wave-rotates: TWO chains (ROR 0x13C + ROL 0x134, runtime
//       direction-probed like R5) -> chain depth 16 (~80 cyc, hidden under
//       ~190 cyc FMA issue). R5's version of this lost only because its
//       weights lived in scratch (VGPR=52, pre-waves_per_eu fix).
//       Tail = R8 all-lane form (bcast_both + cs state), HW-verified absmax 0.

#define LOG2E 1.44269504088896340736f

typedef float f32x2 __attribute__((ext_vector_type(2)));
typedef unsigned uv2 __attribute__((ext_vector_type(2)));
typedef float f32x16 __attribute__((ext_vector_type(16)));
typedef float f32x32 __attribute__((ext_vector_type(32)));

__device__ __forceinline__ float fast_rcp(float x) { return __builtin_amdgcn_rcpf(x); }
__device__ __forceinline__ float fast_exp2(float x) { return __builtin_amdgcn_exp2f(x); }

// permlane32_swap(x,x): r.x = lo-half value in ALL lanes, r.y = hi-half value
// in ALL lanes. HW-verified (R8/R9 ran this exact form, absmax 0.0).
__device__ __forceinline__ f32x2 bcast_both(float x) {
    uv2 r = __builtin_amdgcn_permlane32_swap(__float_as_uint(x), __float_as_uint(x),
                                             false, false);
    f32x2 o;
    o.x = __uint_as_float(r.x);  // lo value, all lanes
    o.y = __uint_as_float(r.y);  // hi value, all lanes
    return o;
}

// wave-level rotate-by-1 DPP (full-rate VALU). 0x13C = WAVE_ROR:1 (verified
// R5), 0x134 = WAVE_ROL:1. Direction is runtime-probed, so a convention
// mismatch cannot silently corrupt results.
#define ROTA(V) __int_as_float(__builtin_amdgcn_mov_dpp(__float_as_int(V), 0x13C, 0xF, 0xF, true))
#define ROTB(V) __int_as_float(__builtin_amdgcn_mov_dpp(__float_as_int(V), 0x134, 0xF, 0xF, true))

// ---------------- K1: projected + prescaled embedding table ----------------
__global__ __launch_bounds__(64, 1) void build_ptab(
    const float4* __restrict__ emb4, const float4* __restrict__ wih4,
    const float* __restrict__ bih, const float* __restrict__ bhh,
    float2* __restrict__ ptab, int nrows) {
    const int lane = threadIdx.x;

    float w0[32], w1[32];
#pragma unroll
    for (int q = 0; q < 8; ++q) {
        float4 a = wih4[lane * 8 + q];
        float4 b = wih4[(lane + 64) * 8 + q];
        w0[4 * q + 0] = a.x; w0[4 * q + 1] = a.y; w0[4 * q + 2] = a.z; w0[4 * q + 3] = a.w;
        w1[4 * q + 0] = b.x; w1[4 * q + 1] = b.y; w1[4 * q + 2] = b.z; w1[4 * q + 3] = b.w;
    }
    const float bias0 = bih[lane] + bhh[lane];
    const float bias1 = bih[lane + 64] + bhh[lane + 64];
    const float s0 = -LOG2E;                                   // rows l: i,f -> sigmoid
    const float s1 = (lane < 32) ? (2.0f * LOG2E) : (-LOG2E);  // rows l+64: g tanh / o sigmoid

    for (int v = blockIdx.x; v < nrows; v += gridDim.x) {
        float a0 = bias0, a1 = bias1;
#pragma unroll
        for (int q = 0; q < 8; ++q) {
            float4 e = emb4[v * 8 + q];  // wave-uniform -> cache broadcast
            a0 = fmaf(e.x, w0[4 * q + 0], a0);
            a0 = fmaf(e.y, w0[4 * q + 1], a0);
            a0 = fmaf(e.z, w0[4 * q + 2], a0);
            a0 = fmaf(e.w, w0[4 * q + 3], a0);
            a1 = fmaf(e.x, w1[4 * q + 0], a1);
            a1 = fmaf(e.y, w1[4 * q + 1], a1);
            a1 = fmaf(e.z, w1[4 * q + 2], a1);
            a1 = fmaf(e.w, w1[4 * q + 3], a1);
        }
        ptab[v * 64 + lane] = make_float2(a0 * s0, a1 * s1);  // coalesced 512B/row
    }
}

// one LSTM step; P = packed {g0,g1} prescaled pre-activations.
// Uses kernel-scope h, cs, wI0, wI1, wA0, wA1, wB0, wB1.
// h, cs valid in ALL 64 lanes (periodic-32); cs = c * 2*log2e.
// Dot: identity slot + chain A (16 RORs) + chain B (15 ROLs) = 32 columns.
#define STEP(P)                                                                \
    do {                                                                       \
        float _a0 = fmaf(h, wI0, (P).x);                                       \
        float _b0 = fmaf(h, wI1, (P).y);                                       \
        float _a1 = 0.0f, _b1 = 0.0f;                                          \
        float _hA = h, _hB = h;                                                \
        _Pragma("unroll") for (int _j = 0; _j < 15; ++_j) {                    \
            _hA = ROTA(_hA);                                                   \
            _a0 = fmaf(_hA, wA0[_j], _a0);                                     \
            _b0 = fmaf(_hA, wA1[_j], _b0);                                     \
            _hB = ROTB(_hB);                                                   \
            _a1 = fmaf(_hB, wB0[_j], _a1);                                     \
            _b1 = fmaf(_hB, wB1[_j], _b1);                                     \
        }                                                                      \
        _hA = ROTA(_hA);                                                       \
        _a0 = fmaf(_hA, wA0[15], _a0);                                         \
        _b0 = fmaf(_hA, wA1[15], _b0);                                         \
        float _A0 = _a0 + _a1; /* lo: y_i*s0, hi: y_f*s0 */                    \
        float _A1 = _b0 + _b1; /* lo: y_g*s1, hi: y_o*s1 */                    \
        float _sg = fast_rcp(1.0f + fast_exp2(_A0)); /* lo:i  hi:f */          \
        float _r1 = fast_rcp(1.0f + fast_exp2(_A1)); /* lo:gf hi:o */          \
        f32x2 _bs = bcast_both(_sg); /* .x=i .y=f (all lanes) */               \
        f32x2 _br = bcast_both(_r1); /* .x=gf .y=o (all lanes) */              \
        float _ggs = fmaf(-4.0f * LOG2E, _br.x, 2.0f * LOG2E); /* tanh(g)*2log2e */ \
        cs = fmaf(_bs.y, cs, _bs.x * _ggs);                                    \
        h = _br.y * fmaf(-2.0f, fast_rcp(1.0f + fast_exp2(cs)), 1.0f);         \
    } while (0)

// ---------------- K2: LSTM scan, one wave per batch element ----------------
template <bool PTAB>
__global__ __launch_bounds__(64)
__attribute__((amdgpu_waves_per_eu(1, 1)))  // pressure target = 1 wave/EU (R6, verified)
void lstm_scan(
    const int* __restrict__ x,
    const float2* __restrict__ ptab,
    const float* __restrict__ emb,
    const float* __restrict__ wih,
    const float* __restrict__ bih,
    const float* __restrict__ bhh,
    const float* __restrict__ whh,
    const float* __restrict__ fcw,
    const float* __restrict__ fcb,
    float* __restrict__ out,
    int S) {
    extern __shared__ int xrow[];
    const int b = blockIdx.x;
    const int lane = threadIdx.x;

    // token ids in LDS, padded so the prefetch ring never reads OOB
    for (int i = lane; i < S + 16; i += 64) xrow[i] = (i < S) ? x[(size_t)b * S + i] : 0;
    __syncthreads();

    const float s0 = -LOG2E;
    const float s1 = (lane < 32) ? (2.0f * LOG2E) : (-LOG2E);

    // probe both wave-rotate directions (wave-uniform); a convention mismatch
    // flips col sign instead of corrupting silently
    int dirA, dirB;
    {
        int gA = __builtin_amdgcn_mov_dpp(lane, 0x13C, 0xF, 0xF, true);
        dirA = (gA == ((lane + 1) & 63)) ? 1 : -1;
        int gB = __builtin_amdgcn_mov_dpp(lane, 0x134, 0xF, 0xF, true);
        dirB = (gB == ((lane + 63) & 63)) ? -1 : 1;
    }

    // recurrent weights, systolic layout, prescaled:
    //   identity slot: col = lane&31
    //   chain A slot j: col = (lane + dirA*(j+1)) & 31, j = 0..15
    //   chain B slot j: col = (lane + dirB*(j+1)) & 31, j = 0..14
    float wI0, wI1;
    f32x16 wA0, wA1, wB0, wB1;
    {
        const int r0 = lane * 32;
        const int r1 = (lane + 64) * 32;
        wI0 = whh[r0 + (lane & 31)] * s0;
        wI1 = whh[r1 + (lane & 31)] * s1;
#pragma unroll
        for (int j = 0; j < 16; ++j) {
            int cA = (lane + dirA * (j + 1)) & 31;
            wA0[j] = whh[r0 + cA] * s0;
            wA1[j] = whh[r1 + cA] * s1;
        }
#pragma unroll
        for (int j = 0; j < 15; ++j) {
            int cB = (lane + dirB * (j + 1)) & 31;
            wB0[j] = whh[r0 + cB] * s0;
            wB1[j] = whh[r1 + cB] * s1;
        }
        wB0[15] = 0.0f;
        wB1[15] = 0.0f;
    }

    float h = 0.0f, cs = 0.0f;  // valid in all 64 lanes (periodic-32); cs = c*2log2e

    if constexpr (PTAB) {
        // 32-bit offset addressing: ptab is 25.6MB, idx<<9 fits unsigned
        const char* pb = (const char*)ptab + (unsigned)(lane << 3);
        // p ring = pre-activations for steps t..t+3; i ring = tokens t+4..t+7
        int i0 = xrow[4], i1 = xrow[5], i2 = xrow[6], i3 = xrow[7];
        f32x2 p0 = *(const f32x2*)(pb + ((unsigned)xrow[0] << 9));
        f32x2 p1 = *(const f32x2*)(pb + ((unsigned)xrow[1] << 9));
        f32x2 p2 = *(const f32x2*)(pb + ((unsigned)xrow[2] << 9));
        f32x2 p3 = *(const f32x2*)(pb + ((unsigned)xrow[3] << 9));
        int t = 0;
        for (; t + 8 <= S; t += 4) {
            STEP(p0); p0 = *(const f32x2*)(pb + ((unsigned)i0 << 9)); i0 = xrow[t + 8];
            STEP(p1); p1 = *(const f32x2*)(pb + ((unsigned)i1 << 9)); i1 = xrow[t + 9];
            STEP(p2); p2 = *(const f32x2*)(pb + ((unsigned)i2 << 9)); i2 = xrow[t + 10];
            STEP(p3); p3 = *(const f32x2*)(pb + ((unsigned)i3 << 9)); i3 = xrow[t + 11];
        }
        if (t + 0 < S) STEP(p0);
        if (t + 1 < S) STEP(p1);
        if (t + 2 < S) STEP(p2);
        if (t + 3 < S) STEP(p3);
        if (t + 4 < S) { f32x2 q = *(const f32x2*)(pb + ((unsigned)i0 << 9)); STEP(q); }
        if (t + 5 < S) { f32x2 q = *(const f32x2*)(pb + ((unsigned)i1 << 9)); STEP(q); }
        if (t + 6 < S) { f32x2 q = *(const f32x2*)(pb + ((unsigned)i2 << 9)); STEP(q); }
    } else {
        // fallback: on-the-fly input projection (workspace too small); cold path
        f32x32 wi0, wi1;
        {
            const float4* wih4 = (const float4*)wih;
#pragma unroll
            for (int q = 0; q < 8; ++q) {
                float4 a = wih4[lane * 8 + q];
                float4 bb = wih4[(lane + 64) * 8 + q];
                wi0[4 * q + 0] = a.x * s0; wi0[4 * q + 1] = a.y * s0;
                wi0[4 * q + 2] = a.z * s0; wi0[4 * q + 3] = a.w * s0;
                wi1[4 * q + 0] = bb.x * s1; wi1[4 * q + 1] = bb.y * s1;
                wi1[4 * q + 2] = bb.z * s1; wi1[4 * q + 3] = bb.w * s1;
            }
        }
        const float bias0 = (bih[lane] + bhh[lane]) * s0;
        const float bias1 = (bih[lane + 64] + bhh[lane + 64]) * s1;
        const float4* emb4 = (const float4*)emb;
        for (int t = 0; t < S; ++t) {
            int idx = xrow[t];
            float a0 = bias0, a1 = bias1;
#pragma unroll
            for (int q = 0; q < 8; ++q) {
                float4 e = emb4[(size_t)idx * 8 + q];
                a0 = fmaf(e.x, wi0[4 * q + 0], a0);
                a0 = fmaf(e.y, wi0[4 * q + 1], a0);
                a0 = fmaf(e.z, wi0[4 * q + 2], a0);
                a0 = fmaf(e.w, wi0[4 * q + 3], a0);
                a1 = fmaf(e.x, wi1[4 * q + 0], a1);
                a1 = fmaf(e.y, wi1[4 * q + 1], a1);
                a1 = fmaf(e.z, wi1[4 * q + 2], a1);
                a1 = fmaf(e.w, wi1[4 * q + 3], a1);
            }
            f32x2 _p; _p.x = a0; _p.y = a1;
            STEP(_p);
        }
    }

    // FC: out[b][n] = sum_k h_k * fc_w[n][k] + fc_b[n]; h periodic-32 ->
    // mask to lanes 0..31 to avoid double counting
    float wv0 = fcw[lane & 31];
    float wv1 = fcw[32 + (lane & 31)];
    float p0v = (lane < 32) ? h * wv0 : 0.0f;
    float p1v = (lane < 32) ? h * wv1 : 0.0f;
#pragma unroll
    for (int m = 32; m >= 1; m >>= 1) {
        p0v += __shfl_xor(p0v, m, 64);
        p1v += __shfl_xor(p1v, m, 64);
    }
    if (lane == 0) {
        out[b * 2 + 0] = p0v + fcb[0];
        out[b * 2 + 1] = p1v + fcb[1];
    }
}

extern "C" void kernel_launch(void* const* d_in, const int* in_sizes, int n_in,
                              void* d_out, int out_size, void* d_ws, size_t ws_size,
                              hipStream_t stream) {
    const int* x = (const int*)d_in[0];
    const float* emb = (const float*)d_in[1];
    const float* wih = (const float*)d_in[2];
    const float* whh = (const float*)d_in[3];
    const float* bih = (const float*)d_in[4];
    const float* bhh = (const float*)d_in[5];
    const float* fcw = (const float*)d_in[6];
    const float* fcb = (const float*)d_in[7];
    float* out = (float*)d_out;

    const int B = out_size / 2;          // 1024
    const int S = in_sizes[0] / B;       // 512
    const int nrows = in_sizes[1] / 32;  // 50001 (EMB=32)

    const size_t need = (size_t)nrows * 64 * sizeof(float2);  // 25.6 MB
    const size_t smem = (size_t)(S + 16) * sizeof(int);

    if (ws_size >= need) {
        float2* ptab = (float2*)d_ws;
        int nb = nrows < 8192 ? nrows : 8192;
        build_ptab<<<nb, 64, 0, stream>>>((const float4*)emb, (const float4*)wih,
                                          bih, bhh, ptab, nrows);
        lstm_scan<true><<<B, 64, smem, stream>>>(x, ptab, emb, wih, bih, bhh, whh,
                                                 fcw, fcb, out, S);
    } else {
        lstm_scan<false><<<B, 64, smem, stream>>>(x, nullptr, emb, wih, bih, bhh, whh,
                                                  fcw, fcb, out, S);
    }
}